// Round 10
// baseline (155.363 us; speedup 1.0000x reference)
//
#include <hip/hip_runtime.h>

#define W_OUT 12
#define N_CAPS 288
#define CIN 8
#define DD 16
#define A_DIM 32
#define B_DIM 4
#define CI 32
#define H_IN 14
#define NT 18            // n-rows per lane (288 / 16)
#define XSTRIDE 12       // x row stride (floats): 48B -> 16B-aligned rows
#define NROWS 576        // 32 ci * 3 ki * 6 jj
#define WCHUNK 2048      // floats per W tile: 16 n-rows * 128 = 8KB

__device__ __forceinline__ float4 shfl_xor4(float4 v, int m) {
    float4 r;
    r.x = __shfl_xor(v.x, m);
    r.y = __shfl_xor(v.y, m);
    r.z = __shfl_xor(v.z, m);
    r.w = __shfl_xor(v.w, m);
    return r;
}

__device__ __forceinline__ void stage_piece(const float* g, float* lds) {
    // async global->LDS DMA, 16B per lane; LDS dest = uniform base + lane*16
    __builtin_amdgcn_global_load_lds(
        (const __attribute__((address_space(1))) void*)g,
        (__attribute__((address_space(3))) void*)lds, 16, 0, 0);
}

__global__ __launch_bounds__(256, 3) void capsule_kernel(
    const float* __restrict__ x,
    const float* __restrict__ Wt,
    const float* __restrict__ bias,
    float* __restrict__ out)
{
    __shared__ __align__(16) float xs[NROWS * XSTRIDE];   // 27648 B
    __shared__ __align__(16) float wbuf[2][WCHUNK];       // 16384 B double buffer
    __shared__ int xoff[N_CAPS];                          // 1152 B

    const int tid = threadIdx.x;
    int bid = blockIdx.x;
    const int jb = bid % 3; bid /= 3;
    const int i  = bid % W_OUT; bid /= W_OUT;
    const int b  = bid % B_DIM; bid /= B_DIM;
    const int a  = bid;
    const int j0 = jb * 4;

    const int lane = tid & 63;
    const int wv   = tid >> 6;          // wave id 0..3 (also the j-site)
    const int dq   = lane & 3;          // d-quad: lane owns d = 4*dq .. 4*dq+3
    const int nr   = lane >> 2;         // n residue: lane owns n = nr + 16*t
    const int swz  = nr & 7;            // read-side XOR swizzle key

    const float* Wa = Wt + (size_t)a * (N_CAPS * CIN * DD);

    // ---- W chunk staging (R10): one cooperative copy per block instead of
    // 4 redundant per-wave L2 streams (R9 was L2-port bound: 2.7 GB @ ~42%
    // VALUBusy flat across R7/R9). Source is XOR-pre-swizzled so the linear
    // LDS dest reads conflict-free (rule 21: swizzle both sides or neither).
    // chunk layout: 512 float4's; logical G = n_loc*32 + c*4 + dq_chunk;
    // LDS slot L holds G = (L&~31) | ((L&31) ^ ((L>>5)&7)).
    auto issue_stage = [&](int t, int buf) {
        #pragma unroll
        for (int k = 0; k < 2; ++k) {
            int p  = wv * 2 + k;              // piece 0..7 (1KB each)
            int L  = p * 64 + lane;           // LDS float4 slot
            int nl = L >> 5;
            int G  = (L & ~31) | ((L & 31) ^ (nl & 7));
            stage_piece(Wa + (size_t)t * WCHUNK + (size_t)G * 4, &wbuf[buf][p * 256]);
        }
    };

    // xoff[n] = LDS float offset of row n's x data (for site sj=0)
    for (int n = tid; n < N_CAPS; n += 256) {
        int ci = n / 9, r = n % 9;
        xoff[n] = (ci * 18 + (r / 3) * 6 + (r % 3)) * XSTRIDE;
    }

    issue_stage(0, 0);   // chunk 0 in flight during x staging

    // stage x window: rows (ci, ki, jj), jj = 0..5 covering sites j0..j0+3
    for (int row = tid; row < NROWS; row += 256) {
        int ci = row / 18, rr = row % 18;
        int ki = rr / 6, jj = rr % 6;
        const float* src = x + ((((size_t)b * CI + ci) * H_IN + (i + ki)) * H_IN + (j0 + jj)) * CIN;
        float4 v0 = *reinterpret_cast<const float4*>(src);
        float4 v1 = *reinterpret_cast<const float4*>(src + 4);
        float* dst = &xs[row * XSTRIDE];
        *reinterpret_cast<float4*>(dst)     = v0;
        *reinterpret_cast<float4*>(dst + 4) = v1;
    }
    const float4 bv = *reinterpret_cast<const float4*>(bias + a * DD + dq * 4);
    __syncthreads();     // drains vmcnt(0): x ready, chunk 0 ready, bias in reg
    issue_stage(1, 1);   // chunk 1 in flight

    const int sjoff = wv * XSTRIDE;

    // ---- priors: ps[t] = prior[n = nr+16t][4dq..4dq+3], W read from LDS.
    // Counted vmcnt (never 0 mid-loop) keeps next chunk's DMA in flight
    // across barriers; sched_barrier(0) fences per rule 18/21.
    float4 ps[NT];
    #pragma unroll
    for (int t = 0; t < NT; ++t) {
        if (t < NT - 1) { asm volatile("s_waitcnt vmcnt(2)" ::: "memory"); }
        else            { asm volatile("s_waitcnt vmcnt(0)" ::: "memory"); }
        __builtin_amdgcn_sched_barrier(0);
        __builtin_amdgcn_s_barrier();                 // chunk t visible to all
        __builtin_amdgcn_sched_barrier(0);

        const int n = nr + 16 * t;
        const float* xp = &xs[xoff[n] + sjoff];
        float xr[CIN];
        *reinterpret_cast<float4*>(&xr[0]) = *reinterpret_cast<const float4*>(xp);
        *reinterpret_cast<float4*>(&xr[4]) = *reinterpret_cast<const float4*>(xp + 4);

        const float4* wb = reinterpret_cast<const float4*>(&wbuf[t & 1][0]);
        float4 acc = {0.f, 0.f, 0.f, 0.f};
        #pragma unroll
        for (int c = 0; c < CIN; ++c) {
            float4 w4 = wb[nr * 32 + (((c << 2) | dq) ^ swz)];
            acc.x = fmaf(xr[c], w4.x, acc.x);
            acc.y = fmaf(xr[c], w4.y, acc.y);
            acc.z = fmaf(xr[c], w4.z, acc.z);
            acc.w = fmaf(xr[c], w4.w, acc.w);
        }
        ps[t] = acc;

        __builtin_amdgcn_sched_barrier(0);
        __builtin_amdgcn_s_barrier();                 // all waves done with buf[t&1]
        __builtin_amdgcn_sched_barrier(0);
        if (t + 2 < NT) issue_stage(t + 2, t & 1);    // overwrite freed buffer
    }

    float lt[NT];     // logits for rows n = nr+16t (replicated across dq lanes)
    float4 out4;

    // ---------- iter 0: logits all zero -> probs = 1/288 ----------
    {
        float4 s = {0.f, 0.f, 0.f, 0.f};
        #pragma unroll
        for (int t = 0; t < NT; ++t) {
            s.x += ps[t].x; s.y += ps[t].y; s.z += ps[t].z; s.w += ps[t].w;
        }
        #pragma unroll
        for (int m = 4; m <= 32; m <<= 1) { float4 o = shfl_xor4(s, m); s.x += o.x; s.y += o.y; s.z += o.z; s.w += o.w; }
        const float inv0 = 1.0f / 288.0f;
        s.x = fmaf(s.x, inv0, bv.x); s.y = fmaf(s.y, inv0, bv.y);
        s.z = fmaf(s.z, inv0, bv.z); s.w = fmaf(s.w, inv0, bv.w);
        float sn = s.x*s.x + s.y*s.y + s.z*s.z + s.w*s.w;
        sn += __shfl_xor(sn, 1); sn += __shfl_xor(sn, 2);
        float factor = sn / (1.0f + sn) * rsqrtf(sn);
        out4.x = factor * s.x; out4.y = factor * s.y; out4.z = factor * s.z; out4.w = factor * s.w;

        #pragma unroll
        for (int t = 0; t < NT; ++t) {
            float p = ps[t].x*out4.x + ps[t].y*out4.y + ps[t].z*out4.z + ps[t].w*out4.w;
            p += __shfl_xor(p, 1);
            p += __shfl_xor(p, 2);
            lt[t] = p;
        }
    }

    // ---------- iters 1, 2 ----------
    #pragma unroll
    for (int it = 1; it < 3; ++it) {
        // lt is REPLICATED across the 4 dq lanes, so softmax reduces must cross
        // nr bits ONLY (masks 4..32) — masks 1,2 would count each residue 4x.
        float m = -1e30f;
        #pragma unroll
        for (int t = 0; t < NT; ++t) m = fmaxf(m, lt[t]);
        #pragma unroll
        for (int msk = 4; msk <= 32; msk <<= 1) m = fmaxf(m, __shfl_xor(m, msk));
        float e[NT];
        float se = 0.f;
        #pragma unroll
        for (int t = 0; t < NT; ++t) { e[t] = __expf(lt[t] - m); se += e[t]; }
        #pragma unroll
        for (int msk = 4; msk <= 32; msk <<= 1) se += __shfl_xor(se, msk);
        const float inv = 1.0f / se;

        float4 s = {0.f, 0.f, 0.f, 0.f};
        #pragma unroll
        for (int t = 0; t < NT; ++t) {
            s.x = fmaf(e[t], ps[t].x, s.x); s.y = fmaf(e[t], ps[t].y, s.y);
            s.z = fmaf(e[t], ps[t].z, s.z); s.w = fmaf(e[t], ps[t].w, s.w);
        }
        #pragma unroll
        for (int msk = 4; msk <= 32; msk <<= 1) { float4 o = shfl_xor4(s, msk); s.x += o.x; s.y += o.y; s.z += o.z; s.w += o.w; }
        s.x = fmaf(s.x, inv, bv.x); s.y = fmaf(s.y, inv, bv.y);
        s.z = fmaf(s.z, inv, bv.z); s.w = fmaf(s.w, inv, bv.w);

        float sn = s.x*s.x + s.y*s.y + s.z*s.z + s.w*s.w;
        sn += __shfl_xor(sn, 1); sn += __shfl_xor(sn, 2);
        float factor = sn / (1.0f + sn) * rsqrtf(sn);
        out4.x = factor * s.x; out4.y = factor * s.y; out4.z = factor * s.z; out4.w = factor * s.w;

        if (it != 2) {
            #pragma unroll
            for (int t = 0; t < NT; ++t) {
                float p = ps[t].x*out4.x + ps[t].y*out4.y + ps[t].z*out4.z + ps[t].w*out4.w;
                p += __shfl_xor(p, 1);
                p += __shfl_xor(p, 2);
                lt[t] += p;
            }
        }
    }

    // ---- store: out[b][a][i][j0+wv][d], 4 lanes (nr==0) x float4 each
    if (nr == 0) {
        size_t o = ((((size_t)b * A_DIM + a) * W_OUT + i) * W_OUT + (j0 + wv)) * DD + dq * 4;
        *reinterpret_cast<float4*>(out + o) = out4;
    }
}

extern "C" void kernel_launch(void* const* d_in, const int* in_sizes, int n_in,
                              void* d_out, int out_size, void* d_ws, size_t ws_size,
                              hipStream_t stream) {
    const float* x    = (const float*)d_in[0];
    const float* Wt   = (const float*)d_in[1];
    const float* bias = (const float*)d_in[2];
    float* out = (float*)d_out;
    (void)in_sizes; (void)n_in; (void)out_size; (void)d_ws; (void)ws_size;

    const int grid = A_DIM * B_DIM * W_OUT * 3;   // 4608 blocks, 4 sites each
    capsule_kernel<<<grid, 256, 0, stream>>>(x, Wt, bias, out);
}